// Round 7
// baseline (183.645 us; speedup 1.0000x reference)
//
#include <hip/hip_runtime.h>
#include <math.h>

#define N_LAYERS 4
#define SEQ      34
#define BATCH_N  16384
#define NE       16        // batch elements per block (lane % 16)
#define NSLOT    8         // query slots per element
#define NT       5         // max positions owned by one slot
#define VOCAB    14
#define SPLIT    17        // h=0 covers j in [0,16]; h=1 covers [17, jmax]
// (1/sqrt(3)) * log2(e): fold attention scale AND exp->exp2 into q
#define QSCALE   0.8329806647638704f

typedef float f32x2 __attribute__((ext_vector_type(2)));

static __device__ __forceinline__ f32x2 mk2(float a, float b) {
    f32x2 r; r.x = a; r.y = b; return r;
}

__global__ __launch_bounds__(256) void addtrans_kernel(
    const int*   __restrict__ idx,      // (B, 34)
    const float* __restrict__ tok_emb,  // (14, 3)
    const float* __restrict__ pos_enc,  // (34, 3)
    const float* __restrict__ ln_w,     // (4, 6)
    const float* __restrict__ ln_b,     // (4, 6)
    const float* __restrict__ q1w,      // (4, 3, 3)
    const float* __restrict__ k1w,
    const float* __restrict__ v1w,
    const float* __restrict__ q2w,
    const float* __restrict__ k2w,
    const float* __restrict__ v2w,
    const float* __restrict__ out_w,    // (4, 6, 6)
    const float* __restrict__ lnf_w,    // (6,)
    const float* __restrict__ lnf_b,    // (6,)
    const float* __restrict__ head_w,   // (14, 6)
    float* __restrict__ out)            // (B, 34, 14)
{
    // K/V for one layer, packed as (head1_i, head2_i) PAIRS, 3 float4/(t,e):
    //   chunk0={k1_0,k2_0,k1_1,k2_1} chunk1={k1_2,k2_2,v1_0,v2_0}
    //   chunk2={v1_1,v2_1,v1_2,v2_2}
    // layout [chunk*SEQ + t][x]. x-dim padded +1: the two h-halves read rows
    // j and j+17 simultaneously; unpadded row stride (64 dwords == 0 mod 32
    // banks) would make that a 4-way conflict, pad keeps it 2-way (free).
    // Row 3*SEQ (pad) absorbs the h1 j+1 prefetch overread at j=33.
    __shared__ float4 kvs[3 * SEQ + 1][NE + 1];

    const int x = threadIdx.x & (NE - 1);      // element
    const int h = (threadIdx.x >> 4) & 1;      // j-range half (shfl_xor 16)
    const int y = threadIdx.x >> 5;            // slot 0..7
    const int b = (int)blockIdx.x * NE + x;

    // R3's balanced row map: slot y owns t = {jmax, y, 8+y, 16+y, 24+y?}
    int tp[NT];
    tp[0] = (y < 2) ? (32 + y) : (24 + y);     // the longest row
    tp[1] = y;
    tp[2] = 8 + y;
    tp[3] = 16 + y;
    tp[4] = (y < 2) ? (24 + y) : -1;           // -1 = absent
    const int jmax = tp[0];

    // Row ownership by half (phase1 staging, residual stream, epilogue, head):
    //   h0 owns rows y, 8+y (k=1,2)  — fully inside j<=16, never merged
    //   h1 owns rows jmax, 16+y, 24+y? (k=0,3,4) — merged from both halves
    bool own[NT];
    own[0] = (h == 1); own[1] = (h == 0); own[2] = (h == 0);
    own[3] = (h == 1); own[4] = (h == 1);

    // ---- embedding (owner lanes only) ----
    float xs[NT][6];
    #pragma unroll
    for (int k = 0; k < NT; ++k) {
        const int t = tp[k];
        if (t >= 0 && own[k]) {
            const int tok = idx[(size_t)b * SEQ + t];
            xs[k][0] = tok_emb[tok * 3 + 0];
            xs[k][1] = tok_emb[tok * 3 + 1];
            xs[k][2] = tok_emb[tok * 3 + 2];
            xs[k][3] = pos_enc[t * 3 + 0];
            xs[k][4] = pos_enc[t * 3 + 1];
            xs[k][5] = pos_enc[t * 3 + 2];
        }
    }

    f32x2 qp[NT][3];

    for (int l = 0; l < N_LAYERS; ++l) {
        __syncthreads();   // WAR: previous layer's attention reads complete

        // init qp (avoids uninitialized reads in the exchange below)
        #pragma unroll
        for (int k = 0; k < NT; ++k)
            qp[k][0] = qp[k][1] = qp[k][2] = mk2(0.f, 0.f);

        // ---- phase 1: owner lanes do LN + q/k/v projections, stage K/V ----
        #pragma unroll
        for (int k = 0; k < NT; ++k) {
            const int t = tp[k];
            if (t >= 0 && own[k]) {
                float hh[6];
                {
                    const float* v = xs[k];
                    float m = (v[0]+v[1]+v[2]+v[3]+v[4]+v[5]) * (1.0f/6.0f);
                    float var = 0.f;
                    #pragma unroll
                    for (int i = 0; i < 6; ++i) { float d = v[i]-m; var += d*d; }
                    var *= (1.0f/6.0f);
                    float r = rsqrtf(var + 1e-5f);
                    #pragma unroll
                    for (int i = 0; i < 6; ++i)
                        hh[i] = (v[i]-m) * r * ln_w[l*6+i] + ln_b[l*6+i];
                }
                float kk[6], vv[6];
                #pragma unroll
                for (int i = 0; i < 3; ++i) {
                    const int w = l*9 + i*3;
                    float q1 = (q1w[w]*hh[0] + q1w[w+1]*hh[1] + q1w[w+2]*hh[2]) * QSCALE;
                    float q2 = (q2w[w]*hh[3] + q2w[w+1]*hh[4] + q2w[w+2]*hh[5]) * QSCALE;
                    qp[k][i] = mk2(q1, q2);
                    kk[i]    =  k1w[w]*hh[0] + k1w[w+1]*hh[1] + k1w[w+2]*hh[2];
                    vv[i]    =  v1w[w]*hh[0] + v1w[w+1]*hh[1] + v1w[w+2]*hh[2];
                    kk[3+i]  =  k2w[w]*hh[3] + k2w[w+1]*hh[4] + k2w[w+2]*hh[5];
                    vv[3+i]  =  v2w[w]*hh[3] + v2w[w+1]*hh[4] + v2w[w+2]*hh[5];
                }
                kvs[0*SEQ + t][x] = make_float4(kk[0], kk[3], kk[1], kk[4]);
                kvs[1*SEQ + t][x] = make_float4(kk[2], kk[5], vv[0], vv[3]);
                kvs[2*SEQ + t][x] = make_float4(vv[1], vv[4], vv[2], vv[5]);
            }
        }

        // ---- qp exchange: both halves need all 5 rows' q-vectors ----
        // partner = lane^16 (same wave). Owners keep theirs; non-owners adopt.
        #pragma unroll
        for (int k = 0; k < NT; ++k) {
            #pragma unroll
            for (int i = 0; i < 3; ++i) {
                float ax = __shfl_xor(qp[k][i].x, 16, 64);
                float ay = __shfl_xor(qp[k][i].y, 16, 64);
                if (!own[k]) qp[k][i] = mk2(ax, ay);
            }
        }
        __syncthreads();   // RAW: K/V visible

        // ---- phase 2: split causal attention, 17 uniform iters per lane ----
        // h=0: j in [0,16]; h=1: j in [17,jmax] (gates mask the overhang).
        // single-pass softmax (no max subtract: |s*log2e| < 46, fp32-safe)
        f32x2 ls[NT], acc[NT][3];
        #pragma unroll
        for (int k = 0; k < NT; ++k) {
            ls[k] = mk2(0.f, 0.f);
            acc[k][0] = acc[k][1] = acc[k][2] = mk2(0.f, 0.f);
        }
        const int jb = h ? SPLIT : 0;
        float4 c0 = kvs[jb][x], c1 = kvs[SEQ + jb][x], c2 = kvs[2*SEQ + jb][x];
        #pragma unroll 2
        for (int jj = 0; jj < SPLIT; ++jj) {
            const int j = jb + jj;
            float4 n0 = kvs[j + 1][x];
            float4 n1 = kvs[SEQ + j + 1][x];
            float4 n2 = kvs[2*SEQ + j + 1][x];
            f32x2 kp0 = mk2(c0.x, c0.y), kp1 = mk2(c0.z, c0.w), kp2 = mk2(c1.x, c1.y);
            f32x2 vp0 = mk2(c1.z, c1.w), vp1 = mk2(c2.x, c2.y), vp2 = mk2(c2.z, c2.w);
            #pragma unroll
            for (int k = 0; k < NT; ++k) {
                if (j <= tp[k]) {             // tp=-1 never fires
                    f32x2 s = qp[k][0]*kp0 + qp[k][1]*kp1 + qp[k][2]*kp2;
                    f32x2 p = mk2(__builtin_amdgcn_exp2f(s.x),
                                  __builtin_amdgcn_exp2f(s.y));
                    ls[k] += p;
                    acc[k][0] += p*vp0; acc[k][1] += p*vp1; acc[k][2] += p*vp2;
                }
            }
            c0 = n0; c1 = n1; c2 = n2;
        }

        // ---- merge halves (rows k=0,3,4 only; k=1,2 complete in h0) ----
        // shfl_xor is symmetric: both lanes end with the full sum.
        #pragma unroll
        for (int k = 0; k < NT; ++k) {
            if (k == 0 || k >= 3) {
                ls[k].x += __shfl_xor(ls[k].x, 16, 64);
                ls[k].y += __shfl_xor(ls[k].y, 16, 64);
                #pragma unroll
                for (int i = 0; i < 3; ++i) {
                    acc[k][i].x += __shfl_xor(acc[k][i].x, 16, 64);
                    acc[k][i].y += __shfl_xor(acc[k][i].y, 16, 64);
                }
            }
        }

        // ---- epilogue (owner lanes): normalize, out projection + residual ----
        #pragma unroll
        for (int k = 0; k < NT; ++k) {
            if (tp[k] >= 0 && own[k]) {
                const float i1 = __builtin_amdgcn_rcpf(ls[k].x);
                const float i2 = __builtin_amdgcn_rcpf(ls[k].y);
                float o[6] = { acc[k][0].x*i1, acc[k][1].x*i1, acc[k][2].x*i1,
                               acc[k][0].y*i2, acc[k][1].y*i2, acc[k][2].y*i2 };
                #pragma unroll
                for (int i = 0; i < 6; ++i) {
                    const int w = l*36 + i*6;
                    xs[k][i] += out_w[w+0]*o[0] + out_w[w+1]*o[1] + out_w[w+2]*o[2]
                              + out_w[w+3]*o[3] + out_w[w+4]*o[4] + out_w[w+5]*o[5];
                }
            }
        }
    }

    // ---- final layernorm + head (owner lanes) ----
    #pragma unroll
    for (int k = 0; k < NT; ++k) {
        const int t = tp[k];
        if (t >= 0 && own[k]) {
            float hf[6];
            {
                const float* v = xs[k];
                float m = (v[0]+v[1]+v[2]+v[3]+v[4]+v[5]) * (1.0f/6.0f);
                float var = 0.f;
                #pragma unroll
                for (int i = 0; i < 6; ++i) { float d = v[i]-m; var += d*d; }
                var *= (1.0f/6.0f);
                float r = rsqrtf(var + 1e-5f);
                #pragma unroll
                for (int i = 0; i < 6; ++i)
                    hf[i] = (v[i]-m) * r * lnf_w[i] + lnf_b[i];
            }
            float lg[VOCAB];
            #pragma unroll
            for (int c = 0; c < VOCAB; ++c) {
                const int w = c*6;
                lg[c] = head_w[w+0]*hf[0] + head_w[w+1]*hf[1] + head_w[w+2]*hf[2]
                      + head_w[w+3]*hf[3] + head_w[w+4]*hf[4] + head_w[w+5]*hf[5];
            }
            float2* op = (float2*)(out + ((size_t)b * SEQ + t) * VOCAB);
            #pragma unroll
            for (int c = 0; c < 7; ++c)
                op[c] = make_float2(lg[2*c], lg[2*c+1]);
        }
    }
}

extern "C" void kernel_launch(void* const* d_in, const int* in_sizes, int n_in,
                              void* d_out, int out_size, void* d_ws, size_t ws_size,
                              hipStream_t stream) {
    const int*   idx     = (const int*)  d_in[0];
    const float* tok_emb = (const float*)d_in[1];
    const float* pos_enc = (const float*)d_in[2];
    const float* ln_w    = (const float*)d_in[3];
    const float* ln_b    = (const float*)d_in[4];
    const float* q1w     = (const float*)d_in[5];
    const float* k1w     = (const float*)d_in[6];
    const float* v1w     = (const float*)d_in[7];
    const float* q2w     = (const float*)d_in[8];
    const float* k2w     = (const float*)d_in[9];
    const float* v2w     = (const float*)d_in[10];
    const float* out_w   = (const float*)d_in[11];
    const float* lnf_w   = (const float*)d_in[12];
    const float* lnf_b   = (const float*)d_in[13];
    const float* head_w  = (const float*)d_in[14];
    float* out = (float*)d_out;

    const int grid = BATCH_N / NE;   // 1024 blocks of 256 threads
    addtrans_kernel<<<grid, 256, 0, stream>>>(
        idx, tok_emb, pos_enc, ln_w, ln_b,
        q1w, k1w, v1w, q2w, k2w, v2w,
        out_w, lnf_w, lnf_b, head_w, out);
}

// Round 8
// 147.966 us; speedup vs baseline: 1.2411x; 1.2411x over previous
//
#include <hip/hip_runtime.h>
#include <math.h>

#define N_LAYERS 4
#define SEQ      34
#define BATCH_N  16384
#define NE       16        // batch elements per block (lane % 16)
#define NSLOT    8         // query slots per element (lane / 16)
#define NT       5         // max positions owned by one slot
#define VOCAB    14
// (1/sqrt(3)) * log2(e): fold attention scale AND exp->exp2 into q
#define QSCALE   0.8329806647638704f

typedef float f32x2 __attribute__((ext_vector_type(2)));

static __device__ __forceinline__ f32x2 mk2(float a, float b) {
    f32x2 r; r.x = a; r.y = b; return r;
}

__global__ __launch_bounds__(128) void addtrans_kernel(
    const int*   __restrict__ idx,      // (B, 34)
    const float* __restrict__ tok_emb,  // (14, 3)
    const float* __restrict__ pos_enc,  // (34, 3)
    const float* __restrict__ ln_w,     // (4, 6)
    const float* __restrict__ ln_b,     // (4, 6)
    const float* __restrict__ q1w,      // (4, 3, 3)
    const float* __restrict__ k1w,
    const float* __restrict__ v1w,
    const float* __restrict__ q2w,
    const float* __restrict__ k2w,
    const float* __restrict__ v2w,
    const float* __restrict__ out_w,    // (4, 6, 6)
    const float* __restrict__ lnf_w,    // (6,)
    const float* __restrict__ lnf_b,    // (6,)
    const float* __restrict__ head_w,   // (14, 6)
    float* __restrict__ out)            // (B, 34, 14)
{
    // K/V for one layer, packed as (head1_i, head2_i) PAIRS, 3 float4/(t,e):
    //   chunk0={k1_0,k2_0,k1_1,k2_1} chunk1={k1_2,k2_2,v1_0,v2_0}
    //   chunk2={v1_1,v2_1,v1_2,v2_2}
    // [t][chunk][x]: row t's 3 chunks are 256 B apart — one address register
    // + ds_read offset immediates in the j-loop. +1 pad row absorbs the j+1
    // prefetch overread.
    __shared__ float4 kvs[SEQ + 1][3][NE];

    const int x = threadIdx.x & (NE - 1);      // element
    const int y = threadIdx.x >> 4;            // slot 0..7
    const int b = (int)blockIdx.x * NE + x;

    // R3's balanced map: slot y owns t = {jmax, y, 8+y, 16+y, 24+y?}; one
    // merged j-loop to jmax serves all (each LDS read amortized 4-5 rows).
    int tp[NT];
    tp[0] = (y < 2) ? (32 + y) : (24 + y);     // the longest row first (unconditional)
    tp[1] = y;
    tp[2] = 8 + y;
    tp[3] = 16 + y;
    tp[4] = (y < 2) ? (24 + y) : -1;           // -1 = absent
    const int jmax = tp[0];

    // ---- embedding ----
    float xs[NT][6];
    #pragma unroll
    for (int k = 0; k < NT; ++k) {
        const int t = tp[k];
        if (t >= 0) {
            const int tok = idx[(size_t)b * SEQ + t];
            xs[k][0] = tok_emb[tok * 3 + 0];
            xs[k][1] = tok_emb[tok * 3 + 1];
            xs[k][2] = tok_emb[tok * 3 + 2];
            xs[k][3] = pos_enc[t * 3 + 0];
            xs[k][4] = pos_enc[t * 3 + 1];
            xs[k][5] = pos_enc[t * 3 + 2];
        }
    }

    // qp[k][i] = (q1_i, q2_i) * QSCALE, a register pair for v_pk_fma_f32
    f32x2 qp[NT][3];

    for (int l = 0; l < N_LAYERS; ++l) {
        __syncthreads();   // WAR: previous layer's attention reads complete

        // ---- phase 1: LN + PACKED q/k/v projections, stage K/V pairs ----
        // weight pairs (w1_i, w2_i) are slot/row-invariant: hoisted out of
        // the k-loop by the compiler; 27 pk-FMA replace 54 scalar FMA.
        #pragma unroll
        for (int k = 0; k < NT; ++k) {
            const int t = tp[k];
            if (t >= 0) {
                float h[6];
                {
                    const float* v = xs[k];
                    float m = (v[0]+v[1]+v[2]+v[3]+v[4]+v[5]) * (1.0f/6.0f);
                    float var = 0.f;
                    #pragma unroll
                    for (int i = 0; i < 6; ++i) { float d = v[i]-m; var += d*d; }
                    var *= (1.0f/6.0f);
                    float r = rsqrtf(var + 1e-5f);
                    #pragma unroll
                    for (int i = 0; i < 6; ++i)
                        h[i] = (v[i]-m) * r * ln_w[l*6+i] + ln_b[l*6+i];
                }
                // hp_j = (h_j, h_{3+j}): head1 uses h[0:3], head2 h[3:6]
                f32x2 hp0 = mk2(h[0], h[3]);
                f32x2 hp1 = mk2(h[1], h[4]);
                f32x2 hp2 = mk2(h[2], h[5]);
                f32x2 kkp[3], vvp[3];
                #pragma unroll
                for (int i = 0; i < 3; ++i) {
                    const int w = l*9 + i*3;
                    f32x2 q = mk2(q1w[w  ], q2w[w  ]) * hp0
                            + mk2(q1w[w+1], q2w[w+1]) * hp1
                            + mk2(q1w[w+2], q2w[w+2]) * hp2;
                    qp[k][i] = q * QSCALE;
                    kkp[i]   = mk2(k1w[w  ], k2w[w  ]) * hp0
                             + mk2(k1w[w+1], k2w[w+1]) * hp1
                             + mk2(k1w[w+2], k2w[w+2]) * hp2;
                    vvp[i]   = mk2(v1w[w  ], v2w[w  ]) * hp0
                             + mk2(v1w[w+1], v2w[w+1]) * hp1
                             + mk2(v1w[w+2], v2w[w+2]) * hp2;
                }
                kvs[t][0][x] = make_float4(kkp[0].x, kkp[0].y, kkp[1].x, kkp[1].y);
                kvs[t][1][x] = make_float4(kkp[2].x, kkp[2].y, vvp[0].x, vvp[0].y);
                kvs[t][2][x] = make_float4(vvp[1].x, vvp[1].y, vvp[2].x, vvp[2].y);
            }
        }
        __syncthreads();   // RAW: K/V visible

        // ---- phase 2: merged causal attention over all owned t's ----
        // single-pass softmax (no max subtract: |s*log2e| < 46, fp32-safe)
        // packed dual-fp32: both heads per v_pk_* instruction
        f32x2 ls[NT], acc[NT][3];
        #pragma unroll
        for (int k = 0; k < NT; ++k) {
            ls[k] = mk2(0.f, 0.f);
            acc[k][0] = acc[k][1] = acc[k][2] = mk2(0.f, 0.f);
        }
        const float4* r0 = &kvs[0][0][x];
        float4 c0 = r0[0*NE], c1 = r0[1*NE], c2 = r0[2*NE];
        #pragma unroll 2
        for (int j = 0; j <= jmax; ++j) {
            const float4* rn = &kvs[j + 1][0][x];
            float4 n0 = rn[0*NE];
            float4 n1 = rn[1*NE];
            float4 n2 = rn[2*NE];
            f32x2 kp0 = mk2(c0.x, c0.y), kp1 = mk2(c0.z, c0.w), kp2 = mk2(c1.x, c1.y);
            f32x2 vp0 = mk2(c1.z, c1.w), vp1 = mk2(c2.x, c2.y), vp2 = mk2(c2.z, c2.w);
            #pragma unroll
            for (int k = 0; k < NT; ++k) {
                if (k == 0 || j <= tp[k]) {   // k=0 unconditional; tp=-1 never fires
                    f32x2 s = qp[k][0]*kp0 + qp[k][1]*kp1 + qp[k][2]*kp2;
                    f32x2 p = mk2(__builtin_amdgcn_exp2f(s.x),
                                  __builtin_amdgcn_exp2f(s.y));
                    ls[k] += p;
                    acc[k][0] += p*vp0; acc[k][1] += p*vp1; acc[k][2] += p*vp2;
                }
            }
            c0 = n0; c1 = n1; c2 = n2;
        }

        // ---- epilogue: normalize, PACKED output projection + residual ----
        #pragma unroll
        for (int k = 0; k < NT; ++k) {
            if (tp[k] >= 0) {
                const f32x2 inv = mk2(__builtin_amdgcn_rcpf(ls[k].x),
                                      __builtin_amdgcn_rcpf(ls[k].y));
                f32x2 op0 = acc[k][0] * inv;   // (o_0, o_3)
                f32x2 op1 = acc[k][1] * inv;   // (o_1, o_4)
                f32x2 op2 = acc[k][2] * inv;   // (o_2, o_5)
                #pragma unroll
                for (int i = 0; i < 6; ++i) {
                    const int w = l*36 + i*6;
                    f32x2 t2 = mk2(out_w[w+0], out_w[w+3]) * op0
                             + mk2(out_w[w+1], out_w[w+4]) * op1
                             + mk2(out_w[w+2], out_w[w+5]) * op2;
                    xs[k][i] += t2.x + t2.y;
                }
            }
        }
    }

    // ---- final layernorm + PACKED head (direct stores, as R3) ----
    #pragma unroll
    for (int k = 0; k < NT; ++k) {
        const int t = tp[k];
        if (t >= 0) {
            float hf[6];
            {
                const float* v = xs[k];
                float m = (v[0]+v[1]+v[2]+v[3]+v[4]+v[5]) * (1.0f/6.0f);
                float var = 0.f;
                #pragma unroll
                for (int i = 0; i < 6; ++i) { float d = v[i]-m; var += d*d; }
                var *= (1.0f/6.0f);
                float r = rsqrtf(var + 1e-5f);
                #pragma unroll
                for (int i = 0; i < 6; ++i)
                    hf[i] = (v[i]-m) * r * lnf_w[i] + lnf_b[i];
            }
            // head rows paired (2c, 2c+1): 6 pk-FMA each yield the float2
            // that is stored directly (same store pattern as R3).
            float2* op = (float2*)(out + ((size_t)b * SEQ + t) * VOCAB);
            #pragma unroll
            for (int c = 0; c < 7; ++c) {
                const int w0 = (2*c) * 6, w1 = (2*c + 1) * 6;
                f32x2 lg = mk2(head_w[w0+0], head_w[w1+0]) * hf[0]
                         + mk2(head_w[w0+1], head_w[w1+1]) * hf[1]
                         + mk2(head_w[w0+2], head_w[w1+2]) * hf[2]
                         + mk2(head_w[w0+3], head_w[w1+3]) * hf[3]
                         + mk2(head_w[w0+4], head_w[w1+4]) * hf[4]
                         + mk2(head_w[w0+5], head_w[w1+5]) * hf[5];
                op[c] = make_float2(lg.x, lg.y);
            }
        }
    }
}

extern "C" void kernel_launch(void* const* d_in, const int* in_sizes, int n_in,
                              void* d_out, int out_size, void* d_ws, size_t ws_size,
                              hipStream_t stream) {
    const int*   idx     = (const int*)  d_in[0];
    const float* tok_emb = (const float*)d_in[1];
    const float* pos_enc = (const float*)d_in[2];
    const float* ln_w    = (const float*)d_in[3];
    const float* ln_b    = (const float*)d_in[4];
    const float* q1w     = (const float*)d_in[5];
    const float* k1w     = (const float*)d_in[6];
    const float* v1w     = (const float*)d_in[7];
    const float* q2w     = (const float*)d_in[8];
    const float* k2w     = (const float*)d_in[9];
    const float* v2w     = (const float*)d_in[10];
    const float* out_w   = (const float*)d_in[11];
    const float* lnf_w   = (const float*)d_in[12];
    const float* lnf_b   = (const float*)d_in[13];
    const float* head_w  = (const float*)d_in[14];
    float* out = (float*)d_out;

    const int grid = BATCH_N / NE;   // 1024 blocks of 128 threads
    addtrans_kernel<<<grid, NE * NSLOT, 0, stream>>>(
        idx, tok_emb, pos_enc, ln_w, ln_b,
        q1w, k1w, v1w, q2w, k2w, v2w,
        out_w, lnf_w, lnf_b, head_w, out);
}